// Round 1
// baseline (1051.911 us; speedup 1.0000x reference)
//
#include <hip/hip_runtime.h>
#include <hip/hip_bf16.h>

#define NB   131072
#define TPB  512
#define SPB  512
#define NSUB 32

typedef __attribute__((ext_vector_type(8))) short short8;
typedef __attribute__((ext_vector_type(4))) float f32x4;

__device__ __forceinline__ unsigned short f2bf(float f) {
    union { float f; unsigned int u; } v; v.f = f;
    unsigned int r = v.u + 0x7fff + ((v.u >> 16) & 1);   // RNE
    return (unsigned short)(r >> 16);
}

// ws layout (ushort elems): [0) Wk2 bf16 row-major [n][k]; [65536) Wk2^T [k][n];
// [131072) Wp2; [196608) Wp2^T.  Total 512 KB.
__global__ void prep_weights(const float* __restrict__ Wk2, const float* __restrict__ Wp2,
                             unsigned short* __restrict__ out) {
    int idx = blockIdx.x * blockDim.x + threadIdx.x;   // 0..65535
    int n = idx >> 8, k = idx & 255;
    unsigned short a = f2bf(Wk2[idx]);
    out[idx] = a;
    out[65536 + k * 256 + n] = a;
    unsigned short b = f2bf(Wp2[idx]);
    out[131072 + idx] = b;
    out[196608 + k * 256 + n] = b;
}

__launch_bounds__(TPB, 2)
__global__ void phgn_main(const float* __restrict__ q_in, const float* __restrict__ p_in,
                          const float* __restrict__ u_in,
                          const float* __restrict__ Wk1, const float* __restrict__ bk1,
                          const float* __restrict__ bk2, const float* __restrict__ wk3,
                          const float* __restrict__ wp1, const float* __restrict__ bp1,
                          const float* __restrict__ bp2, const float* __restrict__ wp3,
                          const float* __restrict__ bctrl,
                          const unsigned short* __restrict__ Wmats,
                          float* __restrict__ out_q, float* __restrict__ out_p) {
    // Activation tile, k-panel layout: elem (m,k) at [ (k>>3)*128 + m*8 + (k&7) ]
    __shared__ unsigned short buf[4096];                 // 8 KB, h1 then g2
    __shared__ float qs[SPB], ps[SPB], gzq[SPB], gzp[SPB];
    __shared__ float svec[2][5][256];                    // per path: wq, wp, b1, w3, b2

    const int tid  = threadIdx.x;
    const int lane = tid & 63;
    const int wave = tid >> 6;      // 0..7, owns n-strip [wave*32, wave*32+32)
    const int g    = lane >> 4;     // quarter-wave 0..3
    const int l15  = lane & 15;

    if (tid < 256) {
        int k = tid;
        svec[0][0][k] = Wk1[2*k];      // dT/dq weight
        svec[0][1][k] = Wk1[2*k+1];    // dT/dp weight
        svec[0][2][k] = bk1[k];
        svec[0][3][k] = wk3[k];
        svec[0][4][k] = bk2[k];
        svec[1][0][k] = wp1[k];        // V path: depends on q only
        svec[1][1][k] = 0.0f;
        svec[1][2][k] = bp1[k];
        svec[1][3][k] = wp3[k];
        svec[1][4][k] = bp2[k];
    }

    const int sg = blockIdx.x * SPB + tid;   // this thread's sample
    const float q0 = q_in[sg], p0 = p_in[sg];
    const float uc = u_in[sg] * bctrl[0];
    float accq = 0.f, accp = 0.f;
    qs[tid] = q0; ps[tid] = p0; gzq[tid] = 0.f; gzp[tid] = 0.f;
    __syncthreads();

    const float dt = 0.05f;

    for (int st = 0; st < 4; ++st) {
        for (int path = 0; path < 2; ++path) {
            const unsigned short* Wf = Wmats + path * 131072;  // [n][k] for fwd B-frags
            const unsigned short* Wb = Wf + 65536;             // [kk][n] for bwd B-frags
            const float* wqv = svec[path][0];
            const float* wpv = svec[path][1];
            const float* b1v = svec[path][2];
            const float* w3v = svec[path][3];
            const float* b2v = svec[path][4];

            // Wave-resident weight fragments: 2 n-tiles x 8 k-steps, fwd + bwd.
            // B-frag for 16x16x32: lane holds B[k = g*8 + i][n = n0 + l15]
            // => contiguous 8 elems along the contraction dim for fixed output col.
            short8 wfr[2][8], wbr[2][8];
            #pragma unroll
            for (int j = 0; j < 2; ++j) {
                const int row = wave*32 + j*16 + l15;
                #pragma unroll
                for (int ks = 0; ks < 8; ++ks) {
                    wfr[j][ks] = *(const short8*)(Wf + row*256 + ks*32 + g*8);
                    wbr[j][ks] = *(const short8*)(Wb + row*256 + ks*32 + g*8);
                }
            }

            for (int t = 0; t < NSUB; ++t) {
                const int m0 = t * 16;
                __syncthreads();   // prev subtile's phase-D reads done

                // ---- Phase A: a1 = wq*q + wp*p + b1 ; h1 = softplus, s1 = sigmoid.
                // Element->thread map matches MFMA C/D layout so s1 stays in regs.
                float s1r[8];
                #pragma unroll
                for (int r = 0; r < 4; ++r) {
                    const int m = g*4 + r;
                    const float qq = qs[m0+m], pp = ps[m0+m];
                    #pragma unroll
                    for (int j = 0; j < 2; ++j) {
                        const int kk = wave*32 + j*16 + l15;
                        const float a  = fmaf(wqv[kk], qq, fmaf(wpv[kk], pp, b1v[kk]));
                        const float e  = __expf(-fabsf(a));
                        const float r1 = __builtin_amdgcn_rcpf(1.0f + e);
                        const float sgm = (a >= 0.f) ? r1 : e * r1;
                        const float hsp = fmaxf(a, 0.f) + __logf(1.0f + e);
                        s1r[r*2+j] = sgm;
                        buf[(kk>>3)*128 + m*8 + (kk&7)] = f2bf(hsp);
                    }
                }
                __syncthreads();

                // ---- Phase B: fwd GEMM  a2[m][n] = sum_k h1[m][k] * W2[n][k]
                f32x4 ac0 = {0,0,0,0}, ac1 = {0,0,0,0};
                #pragma unroll
                for (int ks = 0; ks < 8; ++ks) {
                    const short8 af = *(const short8*)(buf + (ks*4+g)*128 + l15*8);
                    ac0 = __builtin_amdgcn_mfma_f32_16x16x32_bf16(af, wfr[0][ks], ac0, 0,0,0);
                    ac1 = __builtin_amdgcn_mfma_f32_16x16x32_bf16(af, wfr[1][ks], ac1, 0,0,0);
                }
                __syncthreads();   // everyone done reading h1 before overwrite

                // ---- Phase C: g2 = w3 * sigmoid(a2 + b2), write bf16 to buf
                #pragma unroll
                for (int j = 0; j < 2; ++j) {
                    const f32x4 ac = j ? ac1 : ac0;
                    const int kk = wave*32 + j*16 + l15;     // n index
                    const float w3 = w3v[kk], b2 = b2v[kk];
                    #pragma unroll
                    for (int r = 0; r < 4; ++r) {
                        const float a  = ac[r] + b2;
                        const float e  = __expf(-fabsf(a));
                        const float r1 = __builtin_amdgcn_rcpf(1.0f + e);
                        const float sgm = (a >= 0.f) ? r1 : e * r1;
                        buf[(kk>>3)*128 + (g*4+r)*8 + (kk&7)] = f2bf(w3 * sgm);
                    }
                }
                __syncthreads();

                // ---- Phase D: bwd GEMM  g1pre[m][kk] = sum_n g2[m][n] * W2[n][kk]
                f32x4 bc0 = {0,0,0,0}, bc1 = {0,0,0,0};
                #pragma unroll
                for (int ns = 0; ns < 8; ++ns) {
                    const short8 ag = *(const short8*)(buf + (ns*4+g)*128 + l15*8);
                    bc0 = __builtin_amdgcn_mfma_f32_16x16x32_bf16(ag, wbr[0][ns], bc0, 0,0,0);
                    bc1 = __builtin_amdgcn_mfma_f32_16x16x32_bf16(ag, wbr[1][ns], bc1, 0,0,0);
                }

                // ---- Phase E: g1 = g1pre * s1;  gz[c] += sum_k g1*w1[k][c]
                float pq[4] = {0,0,0,0}, pr[4] = {0,0,0,0};
                #pragma unroll
                for (int j = 0; j < 2; ++j) {
                    const f32x4 ac = j ? bc1 : bc0;
                    const int kk = wave*32 + j*16 + l15;
                    const float wq = wqv[kk], wp = wpv[kk];
                    #pragma unroll
                    for (int r = 0; r < 4; ++r) {
                        const float v = ac[r] * s1r[r*2+j];
                        pq[r] = fmaf(v, wq, pq[r]);
                        pr[r] = fmaf(v, wp, pr[r]);
                    }
                }
                #pragma unroll
                for (int off = 1; off < 16; off <<= 1) {
                    #pragma unroll
                    for (int r = 0; r < 4; ++r) {
                        pq[r] += __shfl_xor(pq[r], off, 16);
                        pr[r] += __shfl_xor(pr[r], off, 16);
                    }
                }
                if (l15 == 0) {
                    #pragma unroll
                    for (int r = 0; r < 4; ++r) {
                        atomicAdd(&gzq[m0 + g*4 + r], pq[r]);
                        atomicAdd(&gzp[m0 + g*4 + r], pr[r]);
                    }
                }
            } // subtiles
        } // path

        // ---- stage combine: dq = dH/dp, dp = -dH/dq + u*bc ; RK4 update
        __syncthreads();
        const float dq = gzp[tid];
        const float dp = -gzq[tid] + uc;
        gzq[tid] = 0.f; gzp[tid] = 0.f;
        const float c = (st == 1 || st == 2) ? 2.f : 1.f;
        accq += c * dq; accp += c * dp;
        if (st < 3) {
            const float h = (st == 2) ? dt : 0.5f * dt;
            qs[tid] = q0 + h * dq;
            ps[tid] = p0 + h * dp;
        }
    }

    out_q[sg] = q0 + (dt / 6.f) * accq;
    out_p[sg] = p0 + (dt / 6.f) * accp;
}

extern "C" void kernel_launch(void* const* d_in, const int* in_sizes, int n_in,
                              void* d_out, int out_size, void* d_ws, size_t ws_size,
                              hipStream_t stream) {
    const float* q   = (const float*)d_in[0];
    const float* p   = (const float*)d_in[1];
    const float* u   = (const float*)d_in[2];
    const float* Wk1 = (const float*)d_in[3];
    const float* bk1 = (const float*)d_in[4];
    const float* Wk2 = (const float*)d_in[5];
    const float* bk2 = (const float*)d_in[6];
    const float* Wk3 = (const float*)d_in[7];
    const float* Wp1 = (const float*)d_in[9];
    const float* bp1 = (const float*)d_in[10];
    const float* Wp2 = (const float*)d_in[11];
    const float* bp2 = (const float*)d_in[12];
    const float* Wp3 = (const float*)d_in[13];
    const float* bc  = (const float*)d_in[15];

    unsigned short* wbf = (unsigned short*)d_ws;   // 512 KB used
    prep_weights<<<256, 256, 0, stream>>>(Wk2, Wp2, wbf);

    float* oq = (float*)d_out;
    phgn_main<<<NB / SPB, TPB, 0, stream>>>(q, p, u, Wk1, bk1, bk2, Wk3, Wp1, bp1, bp2, Wp3,
                                            bc, wbf, oq, oq + NB);
}

// Round 2
// 790.137 us; speedup vs baseline: 1.3313x; 1.3313x over previous
//
#include <hip/hip_runtime.h>
#include <hip/hip_bf16.h>

#define NB   131072
#define TPB  1024
#define SPB  512
#define NSUB 32

typedef __attribute__((ext_vector_type(8))) short short8;
typedef __attribute__((ext_vector_type(4))) float f32x4;

__device__ __forceinline__ unsigned short f2bf(float f) {
    union { float f; unsigned int u; } v; v.f = f;
    unsigned int r = v.u + 0x7fff + ((v.u >> 16) & 1);   // RNE
    return (unsigned short)(r >> 16);
}

// ws layout (ushort elems): [0) Wk2 bf16 row-major [n][k]; [65536) Wk2^T [k][n];
// [131072) Wp2; [196608) Wp2^T.  Total 512 KB (L2-resident).
__global__ void prep_weights(const float* __restrict__ Wk2, const float* __restrict__ Wp2,
                             unsigned short* __restrict__ out) {
    int idx = blockIdx.x * blockDim.x + threadIdx.x;   // 0..65535
    int n = idx >> 8, k = idx & 255;
    unsigned short a = f2bf(Wk2[idx]);
    out[idx] = a;
    out[65536 + k * 256 + n] = a;
    unsigned short b = f2bf(Wp2[idx]);
    out[131072 + idx] = b;
    out[196608 + k * 256 + n] = b;
}

// 16 waves; wave w owns fwd output cols [16w,16w+16) and bwd output cols [16w,16w+16).
// Thread's elementwise column col = 16*wave + l15 is identical in phases A/C/E,
// so layer-1 sigmoid (s1) lives in 4 registers between phase A and phase E.
__launch_bounds__(TPB, 4)
__global__ void phgn_main(const float* __restrict__ q_in, const float* __restrict__ p_in,
                          const float* __restrict__ u_in,
                          const float* __restrict__ Wk1, const float* __restrict__ bk1,
                          const float* __restrict__ bk2, const float* __restrict__ wk3,
                          const float* __restrict__ wp1, const float* __restrict__ bp1,
                          const float* __restrict__ bp2, const float* __restrict__ wp3,
                          const float* __restrict__ bctrl,
                          const unsigned short* __restrict__ Wmats,
                          float* __restrict__ out_q, float* __restrict__ out_p) {
    // k-panel layout: elem (m,k) at [(k>>3)*128 + m*8 + (k&7)], 16 rows x 256 cols
    __shared__ unsigned short bufH[4096];   // 8 KB  h1
    __shared__ unsigned short bufG[4096];   // 8 KB  g2
    __shared__ float qs[SPB], ps[SPB], gzq[SPB], gzp[SPB];

    const int tid  = threadIdx.x;
    const int lane = tid & 63;
    const int wave = tid >> 6;      // 0..15
    const int g    = lane >> 4;     // 0..3
    const int l15  = lane & 15;
    const int col  = wave * 16 + l15;   // 0..255

    // Per-column layer-1/3 params, both paths, held in registers (tiny, L2-hot).
    const float wqT = Wk1[2*col], wpT = Wk1[2*col+1], b1T = bk1[col];
    const float w3T = wk3[col],   b2T = bk2[col];
    const float wqV = wp1[col],   b1V = bp1[col];
    const float w3V = wp3[col],   b2V = bp2[col];

    float q0 = 0.f, p0 = 0.f, uc = 0.f, accq = 0.f, accp = 0.f;
    if (tid < SPB) {
        const int sg = blockIdx.x * SPB + tid;
        q0 = q_in[sg]; p0 = p_in[sg];
        uc = u_in[sg] * bctrl[0];
        qs[tid] = q0; ps[tid] = p0; gzq[tid] = 0.f; gzp[tid] = 0.f;
    }
    __syncthreads();

    const float dt = 0.05f;

    for (int st = 0; st < 4; ++st) {
        for (int path = 0; path < 2; ++path) {
            const unsigned short* Wf = Wmats + path * 131072;  // [n][k]
            const unsigned short* Wb = Wf + 65536;             // [k][n]
            const float wq = path ? wqV : wqT;
            const float wp = path ? 0.f : wpT;
            const float b1 = path ? b1V : b1T;
            const float w3 = path ? w3V : w3T;
            const float b2 = path ? b2V : b2T;

            // Weight fragments: 8 k-steps fwd + 8 bwd = 64 VGPRs (no spill at 128 cap).
            short8 wfr[8], wbr[8];
            #pragma unroll
            for (int ks = 0; ks < 8; ++ks) {
                wfr[ks] = *(const short8*)(Wf + col*256 + ks*32 + g*8);
                wbr[ks] = *(const short8*)(Wb + col*256 + ks*32 + g*8);
            }

            for (int t = 0; t < NSUB; ++t) {
                const int m0 = t * 16;

                // ---- Phase A: a1 = wq*q + wp*p + b1; h1 = softplus -> bufH; s1 in regs
                float s1r[4];
                #pragma unroll
                for (int r = 0; r < 4; ++r) {
                    const int m = g*4 + r;
                    const float a  = fmaf(wq, qs[m0+m], fmaf(wp, ps[m0+m], b1));
                    const float e  = __expf(-fabsf(a));
                    const float r1 = __builtin_amdgcn_rcpf(1.0f + e);
                    s1r[r] = (a >= 0.f) ? r1 : e * r1;
                    const float hsp = fmaxf(a, 0.f) + __logf(1.0f + e);
                    bufH[(col>>3)*128 + m*8 + (col&7)] = f2bf(hsp);
                }
                __syncthreads();

                // ---- Phase B: fwd GEMM  a2[m][n] = sum_k h1[m][k] * W2[n][k]
                f32x4 ac = {0,0,0,0};
                #pragma unroll
                for (int ks = 0; ks < 8; ++ks) {
                    const short8 af = *(const short8*)(bufH + (ks*4+g)*128 + l15*8);
                    ac = __builtin_amdgcn_mfma_f32_16x16x32_bf16(af, wfr[ks], ac, 0,0,0);
                }

                // ---- Phase C: g2 = w3 * sigmoid(a2 + b2) -> bufG
                #pragma unroll
                for (int r = 0; r < 4; ++r) {
                    const float a  = ac[r] + b2;
                    const float e  = __expf(-fabsf(a));
                    const float r1 = __builtin_amdgcn_rcpf(1.0f + e);
                    const float sgm = (a >= 0.f) ? r1 : e * r1;
                    bufG[(col>>3)*128 + (g*4+r)*8 + (col&7)] = f2bf(w3 * sgm);
                }
                __syncthreads();

                // ---- Phase D: bwd GEMM  g1pre[m][kk] = sum_n g2[m][n] * W2[n][kk]
                f32x4 bc = {0,0,0,0};
                #pragma unroll
                for (int ns = 0; ns < 8; ++ns) {
                    const short8 ag = *(const short8*)(bufG + (ns*4+g)*128 + l15*8);
                    bc = __builtin_amdgcn_mfma_f32_16x16x32_bf16(ag, wbr[ns], bc, 0,0,0);
                }

                // ---- Phase E: g1 = g1pre * s1; reduce over this wave's 16 kk-cols
                float pq[4], pr[4];
                #pragma unroll
                for (int r = 0; r < 4; ++r) {
                    const float v = bc[r] * s1r[r];
                    pq[r] = v * wq;
                    pr[r] = v * wp;
                }
                #pragma unroll
                for (int off = 1; off < 16; off <<= 1) {
                    #pragma unroll
                    for (int r = 0; r < 4; ++r) {
                        pq[r] += __shfl_xor(pq[r], off, 16);
                        if (path == 0) pr[r] += __shfl_xor(pr[r], off, 16);
                    }
                }
                if (l15 == 0) {
                    #pragma unroll
                    for (int r = 0; r < 4; ++r) {
                        atomicAdd(&gzq[m0 + g*4 + r], pq[r]);
                        if (path == 0) atomicAdd(&gzp[m0 + g*4 + r], pr[r]);
                    }
                }
            } // subtiles
        } // path

        // ---- stage combine: dq = dH/dp, dp = -dH/dq + u*bc; RK4 update
        __syncthreads();   // all phase-E atomics done
        if (tid < SPB) {
            const float dq = gzp[tid];
            const float dp = -gzq[tid] + uc;
            gzq[tid] = 0.f; gzp[tid] = 0.f;
            const float c = (st == 1 || st == 2) ? 2.f : 1.f;
            accq += c * dq; accp += c * dp;
            if (st < 3) {
                const float h = (st == 2) ? dt : 0.5f * dt;
                qs[tid] = q0 + h * dq;
                ps[tid] = p0 + h * dp;
            }
        }
        __syncthreads();   // qs/ps visible before next stage's phase A
    }

    if (tid < SPB) {
        const int sg = blockIdx.x * SPB + tid;
        out_q[sg] = q0 + (dt / 6.f) * accq;
        out_p[sg] = p0 + (dt / 6.f) * accp;
    }
}

extern "C" void kernel_launch(void* const* d_in, const int* in_sizes, int n_in,
                              void* d_out, int out_size, void* d_ws, size_t ws_size,
                              hipStream_t stream) {
    const float* q   = (const float*)d_in[0];
    const float* p   = (const float*)d_in[1];
    const float* u   = (const float*)d_in[2];
    const float* Wk1 = (const float*)d_in[3];
    const float* bk1 = (const float*)d_in[4];
    const float* Wk2 = (const float*)d_in[5];
    const float* bk2 = (const float*)d_in[6];
    const float* Wk3 = (const float*)d_in[7];
    const float* Wp1 = (const float*)d_in[9];
    const float* bp1 = (const float*)d_in[10];
    const float* Wp2 = (const float*)d_in[11];
    const float* bp2 = (const float*)d_in[12];
    const float* Wp3 = (const float*)d_in[13];
    const float* bc  = (const float*)d_in[15];

    unsigned short* wbf = (unsigned short*)d_ws;   // 512 KB used
    prep_weights<<<256, 256, 0, stream>>>(Wk2, Wp2, wbf);

    float* oq = (float*)d_out;
    phgn_main<<<NB / SPB, TPB, 0, stream>>>(q, p, u, Wk1, bk1, bk2, Wk3, Wp1, bp1, bp2, Wp3,
                                            bc, wbf, oq, oq + NB);
}

// Round 3
// 684.519 us; speedup vs baseline: 1.5367x; 1.1543x over previous
//
#include <hip/hip_runtime.h>
#include <hip/hip_bf16.h>

#define NB   131072
#define TPB  1024
#define SPB  512

typedef __attribute__((ext_vector_type(8))) short short8;
typedef __attribute__((ext_vector_type(4))) float f32x4;

__device__ __forceinline__ unsigned short f2bf(float f) {
    union { float f; unsigned int u; } v; v.f = f;
    unsigned int r = v.u + 0x7fff + ((v.u >> 16) & 1);   // RNE
    return (unsigned short)(r >> 16);
}

__device__ __forceinline__ unsigned int cvt_pk_bf16(float lo, float hi) {
    unsigned int r;
    asm("v_cvt_pk_bf16_f32 %0, %1, %2" : "=v"(r) : "v"(lo), "v"(hi));
    return r;
}

// sum over the 16 lanes of a DPP row (l15 group); all lanes end with the total.
__device__ __forceinline__ float row_reduce_add(float x) {
    x += __int_as_float(__builtin_amdgcn_update_dpp(0, __float_as_int(x), 0x128, 0xF, 0xF, true)); // row_ror:8
    x += __int_as_float(__builtin_amdgcn_update_dpp(0, __float_as_int(x), 0x124, 0xF, 0xF, true)); // row_ror:4
    x += __int_as_float(__builtin_amdgcn_update_dpp(0, __float_as_int(x), 0x122, 0xF, 0xF, true)); // row_ror:2
    x += __int_as_float(__builtin_amdgcn_update_dpp(0, __float_as_int(x), 0x121, 0xF, 0xF, true)); // row_ror:1
    return x;
}

// ws layout (ushort elems): [0) Wk2 bf16 [n][k]; [65536) Wk2^T [k][n];
// [131072) Wp2; [196608) Wp2^T.  512 KB, L2-resident.
__global__ void prep_weights(const float* __restrict__ Wk2, const float* __restrict__ Wp2,
                             unsigned short* __restrict__ out) {
    int idx = blockIdx.x * blockDim.x + threadIdx.x;   // 0..65535
    int n = idx >> 8, k = idx & 255;
    unsigned short a = f2bf(Wk2[idx]);
    out[idx] = a;
    out[65536 + k * 256 + n] = a;
    unsigned short b = f2bf(Wp2[idx]);
    out[131072 + idx] = b;
    out[196608 + k * 256 + n] = b;
}

// Phase macros. Thread identity: wave (0..15) owns col-strip [16w,16w+16);
// col = 16*wave + l15 is this thread's column in ALL elementwise phases, so the
// layer-1 sigmoid s1 stays in registers from phase A to phase E (2 tiles later).
// LDS k-panel layout: elem (m,k) at [(k>>3)*128 + m*8 + (k&7)].

#define PH_A(TNEXT, HBUF, S1) do {                                              \
    const int mb_ = (TNEXT) * 16;                                               \
    _Pragma("unroll")                                                           \
    for (int r_ = 0; r_ < 4; r_ += 2) {                                         \
        float ss_[2], hh_[2];                                                   \
        _Pragma("unroll")                                                       \
        for (int u_ = 0; u_ < 2; ++u_) {                                        \
            const int m_ = g*4 + r_ + u_;                                       \
            const float a_  = fmaf(wq, qs[mb_+m_], fmaf(wp, ps[mb_+m_], b1));   \
            const float e_  = __expf(-fabsf(a_));                               \
            const float r1_ = __builtin_amdgcn_rcpf(1.0f + e_);                 \
            ss_[u_] = (a_ >= 0.f) ? r1_ : e_ * r1_;                             \
            hh_[u_] = fmaxf(a_, 0.f) + __logf(1.0f + e_);                       \
        }                                                                       \
        S1[r_] = ss_[0]; S1[r_+1] = ss_[1];                                     \
        const unsigned int pk_ = cvt_pk_bf16(hh_[0], hh_[1]);                   \
        HBUF[(col>>3)*128 + (g*4+r_  )*8 + (col&7)] = (unsigned short)(pk_ & 0xffffu); \
        HBUF[(col>>3)*128 + (g*4+r_+1)*8 + (col&7)] = (unsigned short)(pk_ >> 16);     \
    }                                                                           \
} while (0)

#define PH_B(HBUF, AC) do {                                                     \
    AC = (f32x4){0.f, 0.f, 0.f, 0.f};                                           \
    _Pragma("unroll")                                                           \
    for (int ks_ = 0; ks_ < 8; ++ks_) {                                         \
        const short8 af_ = *(const short8*)(HBUF + (ks_*4+g)*128 + l15*8);      \
        AC = __builtin_amdgcn_mfma_f32_16x16x32_bf16(af_, wfr[ks_], AC, 0,0,0); \
    }                                                                           \
} while (0)

#define PH_C(AC, GBUF) do {                                                     \
    _Pragma("unroll")                                                           \
    for (int r_ = 0; r_ < 4; r_ += 2) {                                         \
        float gg_[2];                                                           \
        _Pragma("unroll")                                                       \
        for (int u_ = 0; u_ < 2; ++u_) {                                        \
            const float a_  = AC[r_+u_] + b2;                                   \
            const float e_  = __expf(-fabsf(a_));                               \
            const float r1_ = __builtin_amdgcn_rcpf(1.0f + e_);                 \
            gg_[u_] = w3 * ((a_ >= 0.f) ? r1_ : e_ * r1_);                      \
        }                                                                       \
        const unsigned int pk_ = cvt_pk_bf16(gg_[0], gg_[1]);                   \
        GBUF[(col>>3)*128 + (g*4+r_  )*8 + (col&7)] = (unsigned short)(pk_ & 0xffffu); \
        GBUF[(col>>3)*128 + (g*4+r_+1)*8 + (col&7)] = (unsigned short)(pk_ >> 16);     \
    }                                                                           \
} while (0)

#define PH_D(GBUF, BC) do {                                                     \
    BC = (f32x4){0.f, 0.f, 0.f, 0.f};                                           \
    _Pragma("unroll")                                                           \
    for (int ns_ = 0; ns_ < 8; ++ns_) {                                         \
        const short8 ag_ = *(const short8*)(GBUF + (ns_*4+g)*128 + l15*8);      \
        BC = __builtin_amdgcn_mfma_f32_16x16x32_bf16(ag_, wbr[ns_], BC, 0,0,0); \
    }                                                                           \
} while (0)

#define PH_E(BC, S1, TPREV) do {                                                \
    const int mb_ = (TPREV) * 16;                                               \
    _Pragma("unroll")                                                           \
    for (int r_ = 0; r_ < 4; ++r_) {                                            \
        const float v_ = BC[r_] * S1[r_];                                       \
        const float sq_ = row_reduce_add(v_ * wq);                              \
        if (l15 == 0) atomicAdd(&gzq[mb_ + g*4 + r_], sq_);                     \
        if (path == 0) {                                                        \
            const float sp_ = row_reduce_add(v_ * wp);                          \
            if (l15 == 0) atomicAdd(&gzp[mb_ + g*4 + r_], sp_);                 \
        }                                                                       \
    }                                                                           \
} while (0)

__launch_bounds__(TPB, 4)
__global__ void phgn_main(const float* __restrict__ q_in, const float* __restrict__ p_in,
                          const float* __restrict__ u_in,
                          const float* __restrict__ Wk1, const float* __restrict__ bk1,
                          const float* __restrict__ bk2, const float* __restrict__ wk3,
                          const float* __restrict__ wp1, const float* __restrict__ bp1,
                          const float* __restrict__ bp2, const float* __restrict__ wp3,
                          const float* __restrict__ bctrl,
                          const unsigned short* __restrict__ Wmats,
                          float* __restrict__ out_q, float* __restrict__ out_p) {
    // Ping-pong tile buffers: one barrier per pipelined iteration.
    __shared__ unsigned short bufH0[4096], bufH1[4096];   // h1, tiles even/odd
    __shared__ unsigned short bufG0[4096], bufG1[4096];   // g2, tiles even/odd
    __shared__ float qs[SPB], ps[SPB], gzq[SPB], gzp[SPB];

    const int tid  = threadIdx.x;
    const int lane = tid & 63;
    const int wave = tid >> 6;      // 0..15
    const int g    = lane >> 4;     // 0..3 (DPP row)
    const int l15  = lane & 15;
    const int col  = wave * 16 + l15;   // 0..255

    // Per-column layer-1/3 params, both paths, in registers.
    const float wqT = Wk1[2*col], wpT = Wk1[2*col+1], b1T = bk1[col];
    const float w3T = wk3[col],   b2T = bk2[col];
    const float wqV = wp1[col],   b1V = bp1[col];
    const float w3V = wp3[col],   b2V = bp2[col];

    float q0 = 0.f, p0 = 0.f, uc = 0.f, accq = 0.f, accp = 0.f;
    if (tid < SPB) {
        const int sg = blockIdx.x * SPB + tid;
        q0 = q_in[sg]; p0 = p_in[sg];
        uc = u_in[sg] * bctrl[0];
        qs[tid] = q0; ps[tid] = p0; gzq[tid] = 0.f; gzp[tid] = 0.f;
    }
    __syncthreads();

    const float dt = 0.05f;

    for (int st = 0; st < 4; ++st) {
        for (int path = 0; path < 2; ++path) {
            const unsigned short* Wf = Wmats + path * 131072;  // [n][k]
            const unsigned short* Wb = Wf + 65536;             // [k][n]
            const float wq = path ? wqV : wqT;
            const float wp = path ? 0.f : wpT;
            const float b1 = path ? b1V : b1T;
            const float w3 = path ? w3V : w3T;
            const float b2 = path ? b2V : b2T;

            short8 wfr[8], wbr[8];
            #pragma unroll
            for (int ks = 0; ks < 8; ++ks) {
                wfr[ks] = *(const short8*)(Wf + col*256 + ks*32 + g*8);
                wbr[ks] = *(const short8*)(Wb + col*256 + ks*32 + g*8);
            }

            f32x4 ac, bc;
            float s1A[4], s1B[4];

            // ---- software pipeline over 32 m-tiles, ONE barrier per iter ----
            PH_A(0, bufH0, s1A);
            __syncthreads();

            // t = 0 (even): no D/E yet
            PH_B(bufH0, ac);
            PH_C(ac, bufG0);
            PH_A(1, bufH1, s1B);
            __syncthreads();

            for (int k2 = 0; k2 < 15; ++k2) {
                const int t0 = 2 * k2;
                // t = t0+1 (odd): B/C(t0+1), D/E(t0 even), A(t0+2 even)
                PH_B(bufH1, ac);
                PH_D(bufG0, bc);
                PH_C(ac, bufG1);
                PH_E(bc, s1A, t0);
                PH_A(t0 + 2, bufH0, s1A);
                __syncthreads();
                // t = t0+2 (even): B/C(t0+2), D/E(t0+1 odd), A(t0+3 odd)
                PH_B(bufH0, ac);
                PH_D(bufG1, bc);
                PH_C(ac, bufG0);
                PH_E(bc, s1B, t0 + 1);
                PH_A(t0 + 3, bufH1, s1B);
                __syncthreads();
            }

            // t = 31 (odd): B/C(31), D/E(30), no A
            PH_B(bufH1, ac);
            PH_D(bufG0, bc);
            PH_C(ac, bufG1);
            PH_E(bc, s1A, 30);
            __syncthreads();

            // t = 32: drain D/E(31)
            PH_D(bufG1, bc);
            PH_E(bc, s1B, 31);
            __syncthreads();
        } // path

        // ---- stage combine: dq = dH/dp, dp = -dH/dq + u*bc; RK4 update
        if (tid < SPB) {
            const float dq = gzp[tid];
            const float dp = -gzq[tid] + uc;
            gzq[tid] = 0.f; gzp[tid] = 0.f;
            const float c = (st == 1 || st == 2) ? 2.f : 1.f;
            accq += c * dq; accp += c * dp;
            if (st < 3) {
                const float h = (st == 2) ? dt : 0.5f * dt;
                qs[tid] = q0 + h * dq;
                ps[tid] = p0 + h * dp;
            }
        }
        __syncthreads();
    }

    if (tid < SPB) {
        const int sg = blockIdx.x * SPB + tid;
        out_q[sg] = q0 + (dt / 6.f) * accq;
        out_p[sg] = p0 + (dt / 6.f) * accp;
    }
}

extern "C" void kernel_launch(void* const* d_in, const int* in_sizes, int n_in,
                              void* d_out, int out_size, void* d_ws, size_t ws_size,
                              hipStream_t stream) {
    const float* q   = (const float*)d_in[0];
    const float* p   = (const float*)d_in[1];
    const float* u   = (const float*)d_in[2];
    const float* Wk1 = (const float*)d_in[3];
    const float* bk1 = (const float*)d_in[4];
    const float* Wk2 = (const float*)d_in[5];
    const float* bk2 = (const float*)d_in[6];
    const float* Wk3 = (const float*)d_in[7];
    const float* Wp1 = (const float*)d_in[9];
    const float* bp1 = (const float*)d_in[10];
    const float* Wp2 = (const float*)d_in[11];
    const float* bp2 = (const float*)d_in[12];
    const float* Wp3 = (const float*)d_in[13];
    const float* bc  = (const float*)d_in[15];

    unsigned short* wbf = (unsigned short*)d_ws;   // 512 KB used
    prep_weights<<<256, 256, 0, stream>>>(Wk2, Wp2, wbf);

    float* oq = (float*)d_out;
    phgn_main<<<NB / SPB, TPB, 0, stream>>>(q, p, u, Wk1, bk1, bk2, Wk3, Wp1, bp1, bp2, Wp3,
                                            bc, wbf, oq, oq + NB);
}

// Round 4
// 571.909 us; speedup vs baseline: 1.8393x; 1.1969x over previous
//
#include <hip/hip_runtime.h>
#include <hip/hip_bf16.h>

#define NB   131072
#define TPB  1024
#define SPB  512

typedef __attribute__((ext_vector_type(8))) short short8;
typedef __attribute__((ext_vector_type(4))) float f32x4;

__device__ __forceinline__ unsigned short f2bf(float f) {
    union { float f; unsigned int u; } v; v.f = f;
    unsigned int r = v.u + 0x7fff + ((v.u >> 16) & 1);   // RNE
    return (unsigned short)(r >> 16);
}

__device__ __forceinline__ unsigned int cvt_pk_bf16(float lo, float hi) {
    unsigned int r;
    asm("v_cvt_pk_bf16_f32 %0, %1, %2" : "=v"(r) : "v"(lo), "v"(hi));
    return r;
}

// sum over the 16 lanes of a DPP row (l15 group); all lanes end with the total.
__device__ __forceinline__ float row_reduce_add(float x) {
    x += __int_as_float(__builtin_amdgcn_update_dpp(0, __float_as_int(x), 0x128, 0xF, 0xF, true)); // row_ror:8
    x += __int_as_float(__builtin_amdgcn_update_dpp(0, __float_as_int(x), 0x124, 0xF, 0xF, true)); // row_ror:4
    x += __int_as_float(__builtin_amdgcn_update_dpp(0, __float_as_int(x), 0x122, 0xF, 0xF, true)); // row_ror:2
    x += __int_as_float(__builtin_amdgcn_update_dpp(0, __float_as_int(x), 0x121, 0xF, 0xF, true)); // row_ror:1
    return x;
}

// ws layout (ushort elems): [0) Wk2 bf16 [n][k]; [65536) Wk2^T [k][n];
// [131072) Wp2; [196608) Wp2^T.  512 KB, L2-resident.
__global__ void prep_weights(const float* __restrict__ Wk2, const float* __restrict__ Wp2,
                             unsigned short* __restrict__ out) {
    int idx = blockIdx.x * blockDim.x + threadIdx.x;   // 0..65535
    int n = idx >> 8, k = idx & 255;
    unsigned short a = f2bf(Wk2[idx]);
    out[idx] = a;
    out[65536 + k * 256 + n] = a;
    unsigned short b = f2bf(Wp2[idx]);
    out[131072 + idx] = b;
    out[196608 + k * 256 + n] = b;
}

// Thread identity: wave (0..15) owns col-strip [16w,16w+16); col = 16*wave + l15
// is this thread's column in ALL elementwise phases, so layer-1 sigmoid s1 stays
// in registers from phase A to phase E.
// LDS k-panel layout: elem (m,k) at [(k>>3)*128 + m*8 + (k&7)].

#define PH_A(TNEXT, HBUF, S1) do {                                              \
    const int mb_ = (TNEXT) * 16;                                               \
    _Pragma("unroll")                                                           \
    for (int r_ = 0; r_ < 4; r_ += 2) {                                         \
        float ss_[2], hh_[2];                                                   \
        _Pragma("unroll")                                                       \
        for (int u_ = 0; u_ < 2; ++u_) {                                        \
            const float2 qp_ = qps[mb_ + g*4 + r_ + u_];                        \
            const float a_  = fmaf(wq, qp_.x, fmaf(wp, qp_.y, b1));             \
            const float e_  = __expf(-fabsf(a_));                               \
            const float r1_ = __builtin_amdgcn_rcpf(1.0f + e_);                 \
            ss_[u_] = (a_ >= 0.f) ? r1_ : e_ * r1_;                             \
            hh_[u_] = fmaxf(a_, 0.f) + __logf(1.0f + e_);                       \
        }                                                                       \
        S1[r_] = ss_[0]; S1[r_+1] = ss_[1];                                     \
        const unsigned int pk_ = cvt_pk_bf16(hh_[0], hh_[1]);                   \
        HBUF[(col>>3)*128 + (g*4+r_  )*8 + (col&7)] = (unsigned short)(pk_ & 0xffffu); \
        HBUF[(col>>3)*128 + (g*4+r_+1)*8 + (col&7)] = (unsigned short)(pk_ >> 16);     \
    }                                                                           \
} while (0)

#define PH_B(HBUF, AC) do {                                                     \
    AC = (f32x4){0.f, 0.f, 0.f, 0.f};                                           \
    _Pragma("unroll")                                                           \
    for (int ks_ = 0; ks_ < 8; ++ks_) {                                         \
        const short8 af_ = *(const short8*)(HBUF + (ks_*4+g)*128 + l15*8);      \
        AC = __builtin_amdgcn_mfma_f32_16x16x32_bf16(af_, wfr[ks_], AC, 0,0,0); \
    }                                                                           \
} while (0)

#define PH_C(AC, GBUF) do {                                                     \
    _Pragma("unroll")                                                           \
    for (int r_ = 0; r_ < 4; r_ += 2) {                                         \
        float gg_[2];                                                           \
        _Pragma("unroll")                                                       \
        for (int u_ = 0; u_ < 2; ++u_) {                                        \
            const float a_  = AC[r_+u_] + b2;                                   \
            const float e_  = __expf(-fabsf(a_));                               \
            const float r1_ = __builtin_amdgcn_rcpf(1.0f + e_);                 \
            gg_[u_] = w3 * ((a_ >= 0.f) ? r1_ : e_ * r1_);                      \
        }                                                                       \
        const unsigned int pk_ = cvt_pk_bf16(gg_[0], gg_[1]);                   \
        GBUF[(col>>3)*128 + (g*4+r_  )*8 + (col&7)] = (unsigned short)(pk_ & 0xffffu); \
        GBUF[(col>>3)*128 + (g*4+r_+1)*8 + (col&7)] = (unsigned short)(pk_ >> 16);     \
    }                                                                           \
} while (0)

#define PH_D(GBUF, BC) do {                                                     \
    BC = (f32x4){0.f, 0.f, 0.f, 0.f};                                           \
    _Pragma("unroll")                                                           \
    for (int ns_ = 0; ns_ < 8; ++ns_) {                                         \
        const short8 ag_ = *(const short8*)(GBUF + (ns_*4+g)*128 + l15*8);      \
        BC = __builtin_amdgcn_mfma_f32_16x16x32_bf16(ag_, wbr[ns_], BC, 0,0,0); \
    }                                                                           \
} while (0)

// Per-wave private gradient slots: gqp[(wave*SPB + m)*2 + {0:q,1:p}].
// Path 0 overwrites (no zero-init needed); path 1 adds to the q slot.
#define PH_E(BC, S1, TPREV) do {                                                \
    const int mb_ = (TPREV) * 16;                                               \
    _Pragma("unroll")                                                           \
    for (int r_ = 0; r_ < 4; ++r_) {                                            \
        const float v_  = BC[r_] * S1[r_];                                      \
        const float sq_ = row_reduce_add(v_ * wq);                              \
        float sp_ = 0.f;                                                        \
        if (path == 0) sp_ = row_reduce_add(v_ * wp);                           \
        if (l15 == 0) {                                                         \
            const int s_ = wave * SPB + mb_ + g*4 + r_;                         \
            if (path == 0) { gqp[2*s_] = sq_; gqp[2*s_+1] = sp_; }              \
            else           { gqp[2*s_] += sq_; }                                \
        }                                                                       \
    }                                                                           \
} while (0)

__launch_bounds__(TPB, 4)
__global__ void phgn_main(const float* __restrict__ q_in, const float* __restrict__ p_in,
                          const float* __restrict__ u_in,
                          const float* __restrict__ Wk1, const float* __restrict__ bk1,
                          const float* __restrict__ bk2, const float* __restrict__ wk3,
                          const float* __restrict__ wp1, const float* __restrict__ bp1,
                          const float* __restrict__ bp2, const float* __restrict__ wp3,
                          const float* __restrict__ bctrl,
                          const unsigned short* __restrict__ Wmats,
                          float* __restrict__ out_q, float* __restrict__ out_p) {
    __shared__ unsigned short bufH0[4096], bufH1[4096];   // h1 tiles (ping-pong)
    __shared__ unsigned short bufG0[4096], bufG1[4096];   // g2 tiles
    __shared__ float2 qps[SPB];                           // (q, p) per sample
    __shared__ float  gqp[16 * SPB * 2];                  // per-wave grad partials, 64 KB

    const int tid  = threadIdx.x;
    const int lane = tid & 63;
    const int wave = tid >> 6;      // 0..15
    const int g    = lane >> 4;     // 0..3 (DPP row)
    const int l15  = lane & 15;
    const int col  = wave * 16 + l15;   // 0..255

    float q0 = 0.f, p0 = 0.f, uc = 0.f, accq = 0.f, accp = 0.f;
    if (tid < SPB) {
        const int sg = blockIdx.x * SPB + tid;
        q0 = q_in[sg]; p0 = p_in[sg];
        uc = u_in[sg] * bctrl[0];
        qps[tid] = make_float2(q0, p0);
    }
    __syncthreads();

    const float dt = 0.05f;

    for (int st = 0; st < 4; ++st) {
        for (int path = 0; path < 2; ++path) {
            const unsigned short* Wf = Wmats + path * 131072;  // [n][k]
            const unsigned short* Wb = Wf + 65536;             // [k][n]
            // Only the current path's params live in registers (L1-hot reloads).
            const float wq = path ? wp1[col] : Wk1[2*col];
            const float wp = path ? 0.f      : Wk1[2*col+1];
            const float b1 = path ? bp1[col] : bk1[col];
            const float w3 = path ? wp3[col] : wk3[col];
            const float b2 = path ? bp2[col] : bk2[col];

            short8 wfr[8], wbr[8];
            #pragma unroll
            for (int ks = 0; ks < 8; ++ks) {
                wfr[ks] = *(const short8*)(Wf + col*256 + ks*32 + g*8);
                wbr[ks] = *(const short8*)(Wb + col*256 + ks*32 + g*8);
            }

            f32x4 ac, bc;
            float s1A[4], s1B[4];

            // ---- software pipeline over 32 m-tiles, ONE barrier per iter ----
            PH_A(0, bufH0, s1A);
            __syncthreads();

            PH_B(bufH0, ac);
            PH_C(ac, bufG0);
            PH_A(1, bufH1, s1B);
            __syncthreads();

            for (int k2 = 0; k2 < 15; ++k2) {
                const int t0 = 2 * k2;
                PH_B(bufH1, ac);
                PH_D(bufG0, bc);
                PH_C(ac, bufG1);
                PH_E(bc, s1A, t0);
                PH_A(t0 + 2, bufH0, s1A);
                __syncthreads();
                PH_B(bufH0, ac);
                PH_D(bufG1, bc);
                PH_C(ac, bufG0);
                PH_E(bc, s1B, t0 + 1);
                PH_A(t0 + 3, bufH1, s1B);
                __syncthreads();
            }

            PH_B(bufH1, ac);
            PH_D(bufG0, bc);
            PH_C(ac, bufG1);
            PH_E(bc, s1A, 30);
            __syncthreads();

            PH_D(bufG1, bc);
            PH_E(bc, s1B, 31);
            __syncthreads();
        } // path

        // ---- stage combine: fold 16 wave-partials; dq = dH/dp, dp = -dH/dq + u*bc
        if (tid < SPB) {
            float sq = 0.f, sp = 0.f;
            #pragma unroll
            for (int w = 0; w < 16; ++w) {
                const float2 v = *(const float2*)&gqp[2 * (w * SPB + tid)];
                sq += v.x; sp += v.y;
            }
            const float dq = sp;
            const float dp = -sq + uc;
            const float c = (st == 1 || st == 2) ? 2.f : 1.f;
            accq += c * dq; accp += c * dp;
            if (st < 3) {
                const float h = (st == 2) ? dt : 0.5f * dt;
                qps[tid] = make_float2(q0 + h * dq, p0 + h * dp);
            }
        }
        __syncthreads();
    }

    if (tid < SPB) {
        const int sg = blockIdx.x * SPB + tid;
        out_q[sg] = q0 + (dt / 6.f) * accq;
        out_p[sg] = p0 + (dt / 6.f) * accp;
    }
}

extern "C" void kernel_launch(void* const* d_in, const int* in_sizes, int n_in,
                              void* d_out, int out_size, void* d_ws, size_t ws_size,
                              hipStream_t stream) {
    const float* q   = (const float*)d_in[0];
    const float* p   = (const float*)d_in[1];
    const float* u   = (const float*)d_in[2];
    const float* Wk1 = (const float*)d_in[3];
    const float* bk1 = (const float*)d_in[4];
    const float* Wk2 = (const float*)d_in[5];
    const float* bk2 = (const float*)d_in[6];
    const float* Wk3 = (const float*)d_in[7];
    const float* Wp1 = (const float*)d_in[9];
    const float* bp1 = (const float*)d_in[10];
    const float* Wp2 = (const float*)d_in[11];
    const float* bp2 = (const float*)d_in[12];
    const float* Wp3 = (const float*)d_in[13];
    const float* bc  = (const float*)d_in[15];

    unsigned short* wbf = (unsigned short*)d_ws;   // 512 KB used
    prep_weights<<<256, 256, 0, stream>>>(Wk2, Wp2, wbf);

    float* oq = (float*)d_out;
    phgn_main<<<NB / SPB, TPB, 0, stream>>>(q, p, u, Wk1, bk1, bk2, Wk3, Wp1, bp1, bp2, Wp3,
                                            bc, wbf, oq, oq + NB);
}